// Round 10
// baseline (160.264 us; speedup 1.0000x reference)
//
#include <hip/hip_runtime.h>
#include <hip/hip_bf16.h>

#define B_N  128
#define VIS  4096
#define HID  4096
#define EMB  512
#define NNEG 2048
#define OUTN (NNEG + 1)
#define SPLIT1 8

using f32x4  = __attribute__((ext_vector_type(4))) float;
using bf16x8 = __attribute__((ext_vector_type(8))) short;

// HW packed f32x2 -> bf16x2 (v_cvt_pk_bf16_f32 on gfx950), RNE.
// union pun because __hip_bfloat162 is not trivially copyable (no bit_cast).
static __device__ __forceinline__ unsigned pk2bf(float x, float y) {
  union { __hip_bfloat162 h; unsigned u; } c;
  c.h = __float22bfloat162_rn(make_float2(x, y));
  return c.u;
}

// 8 fp32 (two float4) -> MFMA A/B fragment, RNE
static __device__ __forceinline__ bf16x8 cvt8(float4 a, float4 b) {
  union { uint4 u; bf16x8 h; } c;
  c.u.x = pk2bf(a.x, a.y); c.u.y = pk2bf(a.z, a.w);
  c.u.z = pk2bf(b.x, b.y); c.u.w = pk2bf(b.z, b.w);
  return c.h;
}

// LDS-only drain + barrier: global loads stay in flight across it.
// R5 lesson: pure-register prefetch without this LDS/barrier anchor gets
// collapsed by the scheduler (loads sunk JIT -> latency-bound).
#define PIPE_BARRIER() __asm__ volatile("s_waitcnt lgkmcnt(0)\n\ts_barrier" ::: "memory")

// GEMM1: Hp[split][128][4096] fp32 partial of vfs @ W_h^T (+b_h split 0).
// grid (64 n-tiles, 8 splits) = 512 blocks (2/CU), 512 thr (8 waves).
// BM=128, BN=64, BK=64, Kchunk=512, 8 K-steps.
// R10: prep fused — A loads fp32 straight from vfs (128 B/row coalesced,
// L2-resident) and converts in-register. W prefetch is a 4-slot rotation
// (32 VGPRs; staging tile k+1 frees its slot for the tile-k+4 load, 3-step
// lookahead covers ~900-cyc HBM latency). Total ~108 VGPR < 128 cap of
// (512,4) — R9 was brushing the cap with the 64-reg whole-chunk scheme.
__global__ __launch_bounds__(512, 4) void gemm1_kernel(
    const float* __restrict__ vfs, const float* __restrict__ Wh,
    const float* __restrict__ bh, float* __restrict__ Hp) {
  const int n0    = blockIdx.x * 64;
  const int kbase = blockIdx.y * 512;

  __shared__ __align__(16) unsigned short Ws[2][64 * 64];  // 16 KB, XOR-swizzled

  const int t = threadIdx.x, w = t >> 6, lane = t & 63;
  const int m_lane = lane & 15, kq = lane >> 4;
  f32x4 acc[4] = {};

  // W staging: 64 rows x 64 cols fp32 per tile; thread t: row t>>3, k-group t&7
  const int wr = t >> 3, wg = t & 7;
  const float* Wg = Wh + (size_t)(n0 + wr) * VIS + kbase + wg * 8;
  const int wofs = wr * 64 + ((wg ^ (wr & 7)) * 8);

  // A: fp32 direct from vfs, row fixed per lane; 2 float4 per frag
  const float* Ag = vfs + (size_t)(w * 16 + m_lane) * VIS + kbase + kq * 8;

  float4 wva[4], wvb[4];   // W rotation, slot = tile & 3
#pragma unroll
  for (int i = 0; i < 4; ++i) {
    wva[i] = *(const float4*)(Wg + i * 64);
    wvb[i] = *(const float4*)(Wg + i * 64 + 4);
  }

  float4 af[2][2][2];      // A tiles fp32, [slot][ks][half]
#pragma unroll
  for (int s = 0; s < 2; ++s)
#pragma unroll
    for (int ks = 0; ks < 2; ++ks) {
      af[s][ks][0] = *(const float4*)(Ag + s * 64 + ks * 32);
      af[s][ks][1] = *(const float4*)(Ag + s * 64 + ks * 32 + 4);
    }

  {
    uint4 pk;
    pk.x = pk2bf(wva[0].x, wva[0].y); pk.y = pk2bf(wva[0].z, wva[0].w);
    pk.z = pk2bf(wvb[0].x, wvb[0].y); pk.w = pk2bf(wvb[0].z, wvb[0].w);
    *(uint4*)&Ws[0][wofs] = pk;
  }
  PIPE_BARRIER();

#pragma unroll
  for (int k = 0; k < 8; ++k) {
    const int cur = k & 1;
    // stage W tile k+1 (frees slot (k+1)&3)
    if (k + 1 < 8) {
      const int s = (k + 1) & 3;
      uint4 pk;
      pk.x = pk2bf(wva[s].x, wva[s].y); pk.y = pk2bf(wva[s].z, wva[s].w);
      pk.z = pk2bf(wvb[s].x, wvb[s].y); pk.w = pk2bf(wvb[s].z, wvb[s].w);
      *(uint4*)&Ws[1 - cur][wofs] = pk;
    }
    // refill W slot k&3 with tile k+4 (tile k was staged at step k-1)
    if (k + 4 < 8) {
      const int s = k & 3;
      wva[s] = *(const float4*)(Wg + (k + 4) * 64);
      wvb[s] = *(const float4*)(Wg + (k + 4) * 64 + 4);
    }
    // convert this step's A frags, then refill the slot with tile k+2
    bf16x8 a0 = cvt8(af[cur][0][0], af[cur][0][1]);
    bf16x8 a1 = cvt8(af[cur][1][0], af[cur][1][1]);
    if (k + 2 < 8) {
#pragma unroll
      for (int ks = 0; ks < 2; ++ks) {
        af[cur][ks][0] = *(const float4*)(Ag + (k + 2) * 64 + ks * 32);
        af[cur][ks][1] = *(const float4*)(Ag + (k + 2) * 64 + ks * 32 + 4);
      }
    }
#pragma unroll
    for (int ks = 0; ks < 2; ++ks) {
      const int Gk = ks * 4 + kq;
      const bf16x8 a = ks ? a1 : a0;
#pragma unroll
      for (int ni = 0; ni < 4; ++ni) {
        const int c = m_lane + ni * 16;
        bf16x8 b = *(const bf16x8*)&Ws[cur][c * 64 + ((Gk ^ (c & 7)) * 8)];
        acc[ni] = __builtin_amdgcn_mfma_f32_16x16x32_bf16(a, b, acc[ni], 0, 0, 0);
      }
    }
    PIPE_BARRIER();
  }

  // epilogue: C/D layout col=lane&15, row=(lane>>4)*4+r; plain fp32 stores
  float* Pd = Hp + (size_t)blockIdx.y * (B_N * HID);
  const int rq = (lane >> 4) * 4;
#pragma unroll
  for (int ni = 0; ni < 4; ++ni) {
    const int ng = n0 + ni * 16 + m_lane;
    const float bias = (blockIdx.y == 0) ? bh[ng] : 0.0f;
#pragma unroll
    for (int r = 0; r < 4; ++r)
      Pd[(size_t)(w * 16 + rq + r) * HID + ng] = acc[ni][r] + bias;
  }
}

// cvt: Hbf = bf16(sum of SPLIT1 Hp planes); also zeroes emb for gemm2 atomics
__global__ __launch_bounds__(256) void cvt_kernel(
    const float* __restrict__ Hp, unsigned short* __restrict__ dst,
    float* __restrict__ emb) {
  const int idx = blockIdx.x * 256 + threadIdx.x;   // 65536 threads, 8 elem each
  const size_t PS = (size_t)B_N * HID;
  float4 a = ((const float4*)Hp)[idx * 2];
  float4 b = ((const float4*)Hp)[idx * 2 + 1];
#pragma unroll
  for (int p = 1; p < SPLIT1; ++p) {
    float4 ap = ((const float4*)(Hp + p * PS))[idx * 2];
    float4 bp = ((const float4*)(Hp + p * PS))[idx * 2 + 1];
    a.x += ap.x; a.y += ap.y; a.z += ap.z; a.w += ap.w;
    b.x += bp.x; b.y += bp.y; b.z += bp.z; b.w += bp.w;
  }
  uint4 pk;
  pk.x = pk2bf(a.x, a.y); pk.y = pk2bf(a.z, a.w);
  pk.z = pk2bf(b.x, b.y); pk.w = pk2bf(b.z, b.w);
  ((uint4*)dst)[idx] = pk;
  if (idx < (B_N * EMB / 4))
    ((float4*)emb)[idx] = make_float4(0.f, 0.f, 0.f, 0.f);
}

// GEMM2: emb[128,512] += hidden(bf16) @ W_e^T (+b_e split 0), fp32 atomics.
// grid (32 n-tiles, 8 splits) = 256 blocks, 512 thr. BM=128 (16 rows/wave),
// BN=16, BK=64, Kchunk=512, 8 K-steps. W chunk (8 float2/thread) issued
// up front, same pipeline as gemm1.
__global__ __launch_bounds__(512, 4) void gemm2_kernel(
    const unsigned short* __restrict__ Hbf, const float* __restrict__ We,
    const float* __restrict__ be, float* __restrict__ emb) {
  const int n0    = blockIdx.x * 16;
  const int kbase = blockIdx.y * 512;

  __shared__ __align__(16) unsigned short Ws[2][16 * 64];  // 4 KB

  const int t = threadIdx.x, w = t >> 6, lane = t & 63;
  const int m_lane = lane & 15, kq = lane >> 4;
  f32x4 acc = {};

  // W staging: 16 rows x 64 cols fp32 per tile, one float2/thread
  const int wr = t >> 5, e = (t & 31) * 2;
  const float* Wg = We + (size_t)(n0 + wr) * HID + kbase + e;
  const int wofs = wr * 64 + (((e >> 3) ^ (wr & 7)) * 8) + (e & 7);

  const unsigned short* Ag = Hbf + (size_t)(w * 16 + m_lane) * HID + kbase + kq * 8;

  float2 wv[8];        // entire W chunk, issued up front
#pragma unroll
  for (int i = 0; i < 8; ++i) wv[i] = *(const float2*)(Wg + i * 64);

  bf16x8 av[3][2];
  av[0][0] = *(const bf16x8*)(Ag);
  av[0][1] = *(const bf16x8*)(Ag + 32);
  av[1][0] = *(const bf16x8*)(Ag + 64);
  av[1][1] = *(const bf16x8*)(Ag + 96);

  *(unsigned*)&Ws[0][wofs] = pk2bf(wv[0].x, wv[0].y);
  PIPE_BARRIER();

#pragma unroll
  for (int k = 0; k < 8; ++k) {
    const int cur = k & 1;
    if (k + 2 < 8) {
      av[(k + 2) % 3][0] = *(const bf16x8*)(Ag + (k + 2) * 64);
      av[(k + 2) % 3][1] = *(const bf16x8*)(Ag + (k + 2) * 64 + 32);
    }
    if (k + 1 < 8) {
      const float2 wc = wv[k + 1];
      *(unsigned*)&Ws[1 - cur][wofs] = pk2bf(wc.x, wc.y);
    }
#pragma unroll
    for (int ks = 0; ks < 2; ++ks) {
      const int Gk = ks * 4 + kq;
      bf16x8 b0 = *(const bf16x8*)&Ws[cur][m_lane * 64 + ((Gk ^ (m_lane & 7)) * 8)];
      acc = __builtin_amdgcn_mfma_f32_16x16x32_bf16(av[k % 3][ks], b0, acc, 0, 0, 0);
    }
    PIPE_BARRIER();
  }

  const int rq = (lane >> 4) * 4;
  const int ng = n0 + m_lane;
  const float bias = (blockIdx.y == 0) ? be[ng] : 0.0f;
#pragma unroll
  for (int r = 0; r < 4; ++r)
    atomicAdd(&emb[(w * 16 + rq + r) * EMB + ng], acc[r] + bias);
}

// Scores, e-stationary. Blocks 0..1023: 16 b x 16 negatives. 1024..1031: positives.
__global__ __launch_bounds__(256, 2) void score_kernel(
    const float* __restrict__ emb, const float* __restrict__ n_lfs,
    const float* __restrict__ p_lfs, float* __restrict__ out) {
  const int bx = blockIdx.x;
  const int t = threadIdx.x;
  const int s = t & 15, tb = t >> 4;

  if (bx < 1024) {
    const int nc = bx >> 3, bt = bx & 7;
    const int n0 = nc * 16, b0 = bt * 16;
    __shared__ __align__(16) float nl[16 * 576];
#pragma unroll
    for (int i = 0; i < 8; ++i) {
      const int f = t + i * 256;
      const int r = f >> 7, o4 = f & 127;
      float4 v = *(const float4*)(n_lfs + (size_t)(n0 + r) * EMB + o4 * 4);
      *(float4*)&nl[r * 576 + (o4 >> 3) * 36 + (o4 & 7) * 4] = v;
    }
    const float* eb = emb + (size_t)(b0 + tb) * EMB + s * 32;
    float4 ev[8];
#pragma unroll
    for (int i = 0; i < 8; ++i) ev[i] = *(const float4*)(eb + i * 4);
    __syncthreads();

    for (int j = 0; j < 16; ++j) {
      const float* nr = &nl[j * 576 + s * 36];
      float a0 = 0.f, a1 = 0.f, a2 = 0.f, a3 = 0.f;
#pragma unroll
      for (int i = 0; i < 8; ++i) {
        float4 nv = *(const float4*)(nr + i * 4);
        float d0 = fmaxf(nv.x - ev[i].x, 0.f);
        float d1 = fmaxf(nv.y - ev[i].y, 0.f);
        float d2 = fmaxf(nv.z - ev[i].z, 0.f);
        float d3 = fmaxf(nv.w - ev[i].w, 0.f);
        a0 = fmaf(d0, d0, a0); a1 = fmaf(d1, d1, a1);
        a2 = fmaf(d2, d2, a2); a3 = fmaf(d3, d3, a3);
      }
      float ss = (a0 + a1) + (a2 + a3);
      ss += __shfl_xor(ss, 1);
      ss += __shfl_xor(ss, 2);
      ss += __shfl_xor(ss, 4);
      ss += __shfl_xor(ss, 8);
      if (s == 0) out[(size_t)(b0 + tb) * OUTN + 1 + n0 + j] = -sqrtf(ss);
    }
  } else {
    const int b = (bx - 1024) * 16 + tb;
    const float* eb = emb + (size_t)b * EMB + s * 32;
    const float* pb = p_lfs + (size_t)b * EMB + s * 32;
    float a0 = 0.f, a1 = 0.f, a2 = 0.f, a3 = 0.f;
#pragma unroll
    for (int i = 0; i < 8; ++i) {
      float4 pv = *(const float4*)(pb + i * 4);
      float4 ev = *(const float4*)(eb + i * 4);
      float d0 = fmaxf(pv.x - ev.x, 0.f);
      float d1 = fmaxf(pv.y - ev.y, 0.f);
      float d2 = fmaxf(pv.z - ev.z, 0.f);
      float d3 = fmaxf(pv.w - ev.w, 0.f);
      a0 = fmaf(d0, d0, a0); a1 = fmaf(d1, d1, a1);
      a2 = fmaf(d2, d2, a2); a3 = fmaf(d3, d3, a3);
    }
    float ss = (a0 + a1) + (a2 + a3);
    ss += __shfl_xor(ss, 1);
    ss += __shfl_xor(ss, 2);
    ss += __shfl_xor(ss, 4);
    ss += __shfl_xor(ss, 8);
    if (s == 0) out[(size_t)b * OUTN] = -sqrtf(ss);
  }
}

extern "C" void kernel_launch(void* const* d_in, const int* in_sizes, int n_in,
                              void* d_out, int out_size, void* d_ws, size_t ws_size,
                              hipStream_t stream) {
  const float* vfs   = (const float*)d_in[0];
  const float* p_lfs = (const float*)d_in[1];
  const float* n_lfs = (const float*)d_in[2];
  const float* W_h   = (const float*)d_in[3];
  const float* b_h   = (const float*)d_in[4];
  const float* W_e   = (const float*)d_in[5];
  const float* b_e   = (const float*)d_in[6];
  float* out = (float*)d_out;

  // ws layout (17.25 MB): [Hp 8x2MB][emb 256KB][Hbf 1MB]
  char* ws = (char*)d_ws;
  float*          Hp  = (float*)ws;
  float*          emb = (float*)(ws + (16u << 20));
  unsigned short* Hbf = (unsigned short*)(ws + (16u << 20) + (256u << 10));

  gemm1_kernel<<<dim3(HID / 64, SPLIT1), 512, 0, stream>>>(vfs, W_h, b_h, Hp);
  cvt_kernel<<<256, 256, 0, stream>>>(Hp, Hbf, emb);
  gemm2_kernel<<<dim3(EMB / 16, 8), 512, 0, stream>>>(Hbf, W_e, b_e, emb);
  score_kernel<<<1032, 256, 0, stream>>>(emb, n_lfs, p_lfs, out);
}

// Round 11
// 155.424 us; speedup vs baseline: 1.0311x; 1.0311x over previous
//
#include <hip/hip_runtime.h>
#include <hip/hip_bf16.h>

#define B_N  128
#define VIS  4096
#define HID  4096
#define EMB  512
#define NNEG 2048
#define OUTN (NNEG + 1)
#define SPLIT1 8
#define SPLIT2 16

using f32x4  = __attribute__((ext_vector_type(4))) float;
using bf16x8 = __attribute__((ext_vector_type(8))) short;

// HW packed f32x2 -> bf16x2 (v_cvt_pk_bf16_f32 on gfx950), RNE.
// union pun because __hip_bfloat162 is not trivially copyable (no bit_cast).
static __device__ __forceinline__ unsigned pk2bf(float x, float y) {
  union { __hip_bfloat162 h; unsigned u; } c;
  c.h = __float22bfloat162_rn(make_float2(x, y));
  return c.u;
}

// LDS-only drain + barrier: global loads stay in flight across it.
// R5 lesson: pure-register prefetch without this LDS/barrier anchor gets
// collapsed by the scheduler (loads sunk JIT -> latency-bound).
#define PIPE_BARRIER() __asm__ volatile("s_waitcnt lgkmcnt(0)\n\ts_barrier" ::: "memory")

// prep: vfs fp32 [128,4096] -> Abf bf16 bits; also zero emb (for gemm2 atomics)
// (R10 post-mortem: fusing this into gemm1 as fp32-A regressed — doubled A-side
// L2 bytes + 8 extra cvts in the hot loop + register-cap pressure. Keep prep.)
__global__ __launch_bounds__(256) void prep_kernel(
    const float* __restrict__ src, unsigned short* __restrict__ dst,
    float* __restrict__ emb) {
  const int idx = blockIdx.x * 256 + threadIdx.x;   // 65536 threads, 8 elem each
  float4 a = ((const float4*)src)[idx * 2];
  float4 b = ((const float4*)src)[idx * 2 + 1];
  uint4 pk;
  pk.x = pk2bf(a.x, a.y); pk.y = pk2bf(a.z, a.w);
  pk.z = pk2bf(b.x, b.y); pk.w = pk2bf(b.z, b.w);
  ((uint4*)dst)[idx] = pk;
  if (idx < (B_N * EMB / 4))
    ((float4*)emb)[idx] = make_float4(0.f, 0.f, 0.f, 0.f);
}

// GEMM1 (R9 config — measured best): Hp[split][128][4096] fp32 partial of
// vfs(bf16) @ W_h^T (+b_h split 0). grid (64 n-tiles, 8 splits) = 512 blocks
// (2/CU), 512 thr (8 waves). BM=128, BN=64, BK=64, Kchunk=512, 8 K-steps.
// W chunk (16 float4/thread) issued entirely in the prologue; consumed via
// cvt -> LDS dbuf -> lgkm-only barrier. A bf16 depth-3 rotation (L2-hot).
__global__ __launch_bounds__(512, 4) void gemm1_kernel(
    const unsigned short* __restrict__ Abf, const float* __restrict__ Wh,
    const float* __restrict__ bh, float* __restrict__ Hp) {
  const int n0    = blockIdx.x * 64;
  const int kbase = blockIdx.y * 512;

  __shared__ __align__(16) unsigned short Ws[2][64 * 64];  // 16 KB, XOR-swizzled

  const int t = threadIdx.x, w = t >> 6, lane = t & 63;
  const int m_lane = lane & 15, kq = lane >> 4;
  f32x4 acc[4] = {};

  // W staging: 64 rows x 64 cols fp32 per tile; thread t: row t>>3, k-group t&7
  const int wr = t >> 3, wg = t & 7;
  const float* Wg = Wh + (size_t)(n0 + wr) * VIS + kbase + wg * 8;
  const int wofs = wr * 64 + ((wg ^ (wr & 7)) * 8);

  // A frags directly from global (L2-hot): row fixed per lane
  const unsigned short* Ag = Abf + (size_t)(w * 16 + m_lane) * VIS + kbase + kq * 8;

  float4 wva[8], wvb[8];   // entire W chunk, issued up front (64 VGPRs)
#pragma unroll
  for (int i = 0; i < 8; ++i) {
    wva[i] = *(const float4*)(Wg + i * 64);
    wvb[i] = *(const float4*)(Wg + i * 64 + 4);
  }

  bf16x8 av[3][2];         // A tiles, rotating [slot][ks]
  av[0][0] = *(const bf16x8*)(Ag);
  av[0][1] = *(const bf16x8*)(Ag + 32);
  av[1][0] = *(const bf16x8*)(Ag + 64);
  av[1][1] = *(const bf16x8*)(Ag + 96);

  {
    uint4 pk;
    pk.x = pk2bf(wva[0].x, wva[0].y); pk.y = pk2bf(wva[0].z, wva[0].w);
    pk.z = pk2bf(wvb[0].x, wvb[0].y); pk.w = pk2bf(wvb[0].z, wvb[0].w);
    *(uint4*)&Ws[0][wofs] = pk;
  }
  PIPE_BARRIER();

#pragma unroll
  for (int k = 0; k < 8; ++k) {
    const int cur = k & 1;
    if (k + 2 < 8) {
      av[(k + 2) % 3][0] = *(const bf16x8*)(Ag + (k + 2) * 64);
      av[(k + 2) % 3][1] = *(const bf16x8*)(Ag + (k + 2) * 64 + 32);
    }
    if (k + 1 < 8) {
      uint4 pk;
      pk.x = pk2bf(wva[k + 1].x, wva[k + 1].y); pk.y = pk2bf(wva[k + 1].z, wva[k + 1].w);
      pk.z = pk2bf(wvb[k + 1].x, wvb[k + 1].y); pk.w = pk2bf(wvb[k + 1].z, wvb[k + 1].w);
      *(uint4*)&Ws[1 - cur][wofs] = pk;
    }
#pragma unroll
    for (int ks = 0; ks < 2; ++ks) {
      const int Gk = ks * 4 + kq;
      const bf16x8 a = av[k % 3][ks];
#pragma unroll
      for (int ni = 0; ni < 4; ++ni) {
        const int c = m_lane + ni * 16;
        bf16x8 b = *(const bf16x8*)&Ws[cur][c * 64 + ((Gk ^ (c & 7)) * 8)];
        acc[ni] = __builtin_amdgcn_mfma_f32_16x16x32_bf16(a, b, acc[ni], 0, 0, 0);
      }
    }
    PIPE_BARRIER();
  }

  // epilogue: C/D layout col=lane&15, row=(lane>>4)*4+r; plain fp32 stores
  float* Pd = Hp + (size_t)blockIdx.y * (B_N * HID);
  const int rq = (lane >> 4) * 4;
#pragma unroll
  for (int ni = 0; ni < 4; ++ni) {
    const int ng = n0 + ni * 16 + m_lane;
    const float bias = (blockIdx.y == 0) ? bh[ng] : 0.0f;
#pragma unroll
    for (int r = 0; r < 4; ++r)
      Pd[(size_t)(w * 16 + rq + r) * HID + ng] = acc[ni][r] + bias;
  }
}

// cvt: Hbf = bf16(sum of SPLIT1 Hp planes); fused split-K reduce + downconvert
__global__ __launch_bounds__(256) void cvt_kernel(
    const float* __restrict__ Hp, unsigned short* __restrict__ dst) {
  const int idx = blockIdx.x * 256 + threadIdx.x;   // 65536 threads, 8 elem each
  const size_t PS = (size_t)B_N * HID;
  float4 a = ((const float4*)Hp)[idx * 2];
  float4 b = ((const float4*)Hp)[idx * 2 + 1];
#pragma unroll
  for (int p = 1; p < SPLIT1; ++p) {
    float4 ap = ((const float4*)(Hp + p * PS))[idx * 2];
    float4 bp = ((const float4*)(Hp + p * PS))[idx * 2 + 1];
    a.x += ap.x; a.y += ap.y; a.z += ap.z; a.w += ap.w;
    b.x += bp.x; b.y += bp.y; b.z += bp.z; b.w += bp.w;
  }
  uint4 pk;
  pk.x = pk2bf(a.x, a.y); pk.y = pk2bf(a.z, a.w);
  pk.z = pk2bf(b.x, b.y); pk.w = pk2bf(b.z, b.w);
  ((uint4*)dst)[idx] = pk;
}

// GEMM2: emb[128,512] += hidden(bf16) @ W_e^T (+b_e split 0), fp32 atomics.
// R11: split-K 8 -> 16: grid (32 n-tiles, 16 splits) = 512 blocks (2/CU) —
// gemm2 was 1 block/CU (the R3 under-subscription failure mode). Kchunk=256,
// 4 K-steps, W chunk (4 float2/thread) issued up front. 16-way atomic
// contention on 64K addresses is ~1M pipelined L2 atomics (~1-2 us), covered
// by the doubled overlap.
__global__ __launch_bounds__(512, 4) void gemm2_kernel(
    const unsigned short* __restrict__ Hbf, const float* __restrict__ We,
    const float* __restrict__ be, float* __restrict__ emb) {
  const int n0    = blockIdx.x * 16;
  const int kbase = blockIdx.y * 256;

  __shared__ __align__(16) unsigned short Ws[2][16 * 64];  // 4 KB

  const int t = threadIdx.x, w = t >> 6, lane = t & 63;
  const int m_lane = lane & 15, kq = lane >> 4;
  f32x4 acc = {};

  // W staging: 16 rows x 64 cols fp32 per tile, one float2/thread
  const int wr = t >> 5, e = (t & 31) * 2;
  const float* Wg = We + (size_t)(n0 + wr) * HID + kbase + e;
  const int wofs = wr * 64 + (((e >> 3) ^ (wr & 7)) * 8) + (e & 7);

  const unsigned short* Ag = Hbf + (size_t)(w * 16 + m_lane) * HID + kbase + kq * 8;

  float2 wv[4];        // entire W chunk (4 tiles), issued up front
#pragma unroll
  for (int i = 0; i < 4; ++i) wv[i] = *(const float2*)(Wg + i * 64);

  bf16x8 av[3][2];
  av[0][0] = *(const bf16x8*)(Ag);
  av[0][1] = *(const bf16x8*)(Ag + 32);
  av[1][0] = *(const bf16x8*)(Ag + 64);
  av[1][1] = *(const bf16x8*)(Ag + 96);

  *(unsigned*)&Ws[0][wofs] = pk2bf(wv[0].x, wv[0].y);
  PIPE_BARRIER();

#pragma unroll
  for (int k = 0; k < 4; ++k) {
    const int cur = k & 1;
    if (k + 2 < 4) {
      av[(k + 2) % 3][0] = *(const bf16x8*)(Ag + (k + 2) * 64);
      av[(k + 2) % 3][1] = *(const bf16x8*)(Ag + (k + 2) * 64 + 32);
    }
    if (k + 1 < 4) {
      const float2 wc = wv[k + 1];
      *(unsigned*)&Ws[1 - cur][wofs] = pk2bf(wc.x, wc.y);
    }
#pragma unroll
    for (int ks = 0; ks < 2; ++ks) {
      const int Gk = ks * 4 + kq;
      bf16x8 b0 = *(const bf16x8*)&Ws[cur][m_lane * 64 + ((Gk ^ (m_lane & 7)) * 8)];
      acc = __builtin_amdgcn_mfma_f32_16x16x32_bf16(av[k % 3][ks], b0, acc, 0, 0, 0);
    }
    PIPE_BARRIER();
  }

  const int rq = (lane >> 4) * 4;
  const int ng = n0 + m_lane;
  const float bias = (blockIdx.y == 0) ? be[ng] : 0.0f;
#pragma unroll
  for (int r = 0; r < 4; ++r)
    atomicAdd(&emb[(w * 16 + rq + r) * EMB + ng], acc[r] + bias);
}

// Scores, e-stationary. Blocks 0..1023: 16 b x 16 negatives. 1024..1031: positives.
__global__ __launch_bounds__(256, 2) void score_kernel(
    const float* __restrict__ emb, const float* __restrict__ n_lfs,
    const float* __restrict__ p_lfs, float* __restrict__ out) {
  const int bx = blockIdx.x;
  const int t = threadIdx.x;
  const int s = t & 15, tb = t >> 4;

  if (bx < 1024) {
    const int nc = bx >> 3, bt = bx & 7;
    const int n0 = nc * 16, b0 = bt * 16;
    __shared__ __align__(16) float nl[16 * 576];
#pragma unroll
    for (int i = 0; i < 8; ++i) {
      const int f = t + i * 256;
      const int r = f >> 7, o4 = f & 127;
      float4 v = *(const float4*)(n_lfs + (size_t)(n0 + r) * EMB + o4 * 4);
      *(float4*)&nl[r * 576 + (o4 >> 3) * 36 + (o4 & 7) * 4] = v;
    }
    const float* eb = emb + (size_t)(b0 + tb) * EMB + s * 32;
    float4 ev[8];
#pragma unroll
    for (int i = 0; i < 8; ++i) ev[i] = *(const float4*)(eb + i * 4);
    __syncthreads();

    for (int j = 0; j < 16; ++j) {
      const float* nr = &nl[j * 576 + s * 36];
      float a0 = 0.f, a1 = 0.f, a2 = 0.f, a3 = 0.f;
#pragma unroll
      for (int i = 0; i < 8; ++i) {
        float4 nv = *(const float4*)(nr + i * 4);
        float d0 = fmaxf(nv.x - ev[i].x, 0.f);
        float d1 = fmaxf(nv.y - ev[i].y, 0.f);
        float d2 = fmaxf(nv.z - ev[i].z, 0.f);
        float d3 = fmaxf(nv.w - ev[i].w, 0.f);
        a0 = fmaf(d0, d0, a0); a1 = fmaf(d1, d1, a1);
        a2 = fmaf(d2, d2, a2); a3 = fmaf(d3, d3, a3);
      }
      float ss = (a0 + a1) + (a2 + a3);
      ss += __shfl_xor(ss, 1);
      ss += __shfl_xor(ss, 2);
      ss += __shfl_xor(ss, 4);
      ss += __shfl_xor(ss, 8);
      if (s == 0) out[(size_t)(b0 + tb) * OUTN + 1 + n0 + j] = -sqrtf(ss);
    }
  } else {
    const int b = (bx - 1024) * 16 + tb;
    const float* eb = emb + (size_t)b * EMB + s * 32;
    const float* pb = p_lfs + (size_t)b * EMB + s * 32;
    float a0 = 0.f, a1 = 0.f, a2 = 0.f, a3 = 0.f;
#pragma unroll
    for (int i = 0; i < 8; ++i) {
      float4 pv = *(const float4*)(pb + i * 4);
      float4 ev = *(const float4*)(eb + i * 4);
      float d0 = fmaxf(pv.x - ev.x, 0.f);
      float d1 = fmaxf(pv.y - ev.y, 0.f);
      float d2 = fmaxf(pv.z - ev.z, 0.f);
      float d3 = fmaxf(pv.w - ev.w, 0.f);
      a0 = fmaf(d0, d0, a0); a1 = fmaf(d1, d1, a1);
      a2 = fmaf(d2, d2, a2); a3 = fmaf(d3, d3, a3);
    }
    float ss = (a0 + a1) + (a2 + a3);
    ss += __shfl_xor(ss, 1);
    ss += __shfl_xor(ss, 2);
    ss += __shfl_xor(ss, 4);
    ss += __shfl_xor(ss, 8);
    if (s == 0) out[(size_t)b * OUTN] = -sqrtf(ss);
  }
}

extern "C" void kernel_launch(void* const* d_in, const int* in_sizes, int n_in,
                              void* d_out, int out_size, void* d_ws, size_t ws_size,
                              hipStream_t stream) {
  const float* vfs   = (const float*)d_in[0];
  const float* p_lfs = (const float*)d_in[1];
  const float* n_lfs = (const float*)d_in[2];
  const float* W_h   = (const float*)d_in[3];
  const float* b_h   = (const float*)d_in[4];
  const float* W_e   = (const float*)d_in[5];
  const float* b_e   = (const float*)d_in[6];
  float* out = (float*)d_out;

  // ws layout (18.25 MB): [Hp 8x2MB][emb 256KB][Abf 1MB][Hbf 1MB]
  char* ws = (char*)d_ws;
  float*          Hp  = (float*)ws;
  float*          emb = (float*)(ws + (16u << 20));
  unsigned short* Abf = (unsigned short*)(ws + (16u << 20) + (256u << 10));
  unsigned short* Hbf = (unsigned short*)(ws + (17u << 20) + (256u << 10));

  prep_kernel<<<256, 256, 0, stream>>>(vfs, Abf, emb);
  gemm1_kernel<<<dim3(HID / 64, SPLIT1), 512, 0, stream>>>(Abf, W_h, b_h, Hp);
  cvt_kernel<<<256, 256, 0, stream>>>(Hp, Hbf);
  gemm2_kernel<<<dim3(EMB / 16, SPLIT2), 512, 0, stream>>>(Hbf, W_e, b_e, emb);
  score_kernel<<<1032, 256, 0, stream>>>(emb, n_lfs, p_lfs, out);
}